// Round 12
// baseline (179.982 us; speedup 1.0000x reference)
//
#include <hip/hip_runtime.h>

#define NN   32
#define EMB  128
#define PEMB 64
#define ENCD 256
#define NLAY 4
#define W1C  261   // 2*EMB + 2*NCLS + 1
#define IND  193   // PEMB + 1 + EMB
#define UPAD 132   // padded row (floats): +16B breaks bank patterns
#define TSCALE 2.885390081777927f   // 2*log2(e): tanh(x) = 1 - 2/(exp2(TSCALE*x)+1)

typedef __attribute__((ext_vector_type(8))) short short8;
typedef __attribute__((ext_vector_type(4))) float floatx4;

// ---- pre-converted weight fragments (bf16 hi/lo, PRE-SCALED by TSCALE), filled by wconv ----
__device__ unsigned short g_wC_h[16384 * 8], g_wC_l[16384 * 8];   // W1 frags
__device__ unsigned short g_wD_h[8192 * 8],  g_wD_l[8192 * 8];    // W2 frags
__device__ unsigned short g_wE1_h[16384 * 8], g_wE1_l[16384 * 8]; // UW1 frags
__device__ unsigned short g_wE2_h[8192 * 8],  g_wE2_l[8192 * 8];  // UW2 frags

// tanh(x) = 1 - 2/(exp(2x)+1)   (Phase A only; unscaled weights there)
__device__ __forceinline__ float fast_tanh(float x) {
  float e = __expf(2.0f * x);
  return 1.0f - __fdividef(2.0f, e + 1.0f);
}
// tanh from PRE-SCALED input s = 2*log2(e)*x : exp2 + add + rcp + fma
__device__ __forceinline__ float tanh2(float s) {
  float e;
  asm("v_exp_f32 %0, %1" : "=v"(e) : "v"(s));
  const float ep1 = e + 1.0f;
  float r;
  asm("v_rcp_f32 %0, %1" : "=v"(r) : "v"(ep1));
  return __builtin_fmaf(-2.0f, r, 1.0f);
}
// fp32 -> bf16 RNE
__device__ __forceinline__ unsigned short f2bf(float x) {
  unsigned u = __float_as_uint(x);
  return (unsigned short)((u + 0x7fffu + ((u >> 16) & 1u)) >> 16);
}
__device__ __forceinline__ float bf2f(unsigned short h) {
  return __uint_as_float(((unsigned)h) << 16);
}
// hw packed convert: dst.lo16 = bf16(a), dst.hi16 = bf16(b)
__device__ __forceinline__ unsigned cvtpk(float a, float b) {
  unsigned r;
  asm("v_cvt_pk_bf16_f32 %0, %1, %2" : "=v"(r) : "v"(a), "v"(b));
  return r;
}

// A*B with A,B split hi/lo bf16 (drop lo*lo): 3 MFMAs
__device__ __forceinline__ floatx4 mfma3(short8 ah, short8 al, short8 bh, short8 bl, floatx4 acc) {
  acc = __builtin_amdgcn_mfma_f32_16x16x32_bf16(ah, bh, acc, 0, 0, 0);
  acc = __builtin_amdgcn_mfma_f32_16x16x32_bf16(al, bh, acc, 0, 0, 0);
  acc = __builtin_amdgcn_mfma_f32_16x16x32_bf16(ah, bl, acc, 0, 0, 0);
  return acc;
}

// one fragment plane p (jt=p&1, kstep=p>>1) from fp32 [NN][UPAD] -> hi/lo frag LDS
__device__ __forceinline__ void cvt_plane(const float (*src)[UPAD],
                                          unsigned short (*dH)[64][8],
                                          unsigned short (*dL)[64][8],
                                          int p, int lane) {
  const int row  = (lane & 15) + ((p & 1) << 4);
  const int koff = ((p >> 1) << 5) + ((lane >> 4) << 3);
  float x[8];
  *(float4*)&x[0] = *(const float4*)&src[row][koff];
  *(float4*)&x[4] = *(const float4*)&src[row][koff + 4];
  unsigned h[4], lo[4];
  #pragma unroll
  for (int q = 0; q < 4; q++) {
    h[q] = cvtpk(x[2*q], x[2*q+1]);
    const float r0 = x[2*q]   - __uint_as_float(h[q] << 16);
    const float r1 = x[2*q+1] - __uint_as_float(h[q] & 0xffff0000u);
    lo[q] = cvtpk(r0, r1);
  }
  *(uint4*)&dH[p][lane][0] = make_uint4(h[0], h[1], h[2], h[3]);
  *(uint4*)&dL[p][lane][0] = make_uint4(lo[0], lo[1], lo[2], lo[3]);
}

// build 4 bf16 t-values for jt0 and jt1 from one float4 slice each (tight live range)
__device__ __forceinline__ void build2q(const float4 u, const float4 va, const float4 vb,
                                        const float4 c, float d0, float d1,
                                        unsigned* o0, unsigned* o1) {
  const float a0 = tanh2(u.x + va.x + d0 * c.x);
  const float a1 = tanh2(u.y + va.y + d0 * c.y);
  const float a2 = tanh2(u.z + va.z + d0 * c.z);
  const float a3 = tanh2(u.w + va.w + d0 * c.w);
  o0[0] = cvtpk(a0, a1); o0[1] = cvtpk(a2, a3);
  const float b0 = tanh2(u.x + vb.x + d1 * c.x);
  const float b1 = tanh2(u.y + vb.y + d1 * c.y);
  const float b2 = tanh2(u.z + vb.z + d1 * c.z);
  const float b3 = tanh2(u.w + vb.w + d1 * c.w);
  o1[0] = cvtpk(b0, b1); o1[1] = cvtpk(b2, b3);
}

__device__ __forceinline__ float dot16_lds(const float* base, const float* wreg) {
  const float4 a = *(const float4*)(base);
  const float4 b = *(const float4*)(base + 4);
  const float4 c = *(const float4*)(base + 8);
  const float4 d = *(const float4*)(base + 12);
  return a.x*wreg[0] + a.y*wreg[1] + a.z*wreg[2]  + a.w*wreg[3]
       + b.x*wreg[4] + b.y*wreg[5] + b.z*wreg[6]  + b.w*wreg[7]
       + c.x*wreg[8] + c.y*wreg[9] + c.z*wreg[10] + c.w*wreg[11]
       + d.x*wreg[12]+ d.y*wreg[13]+ d.z*wreg[14] + d.w*wreg[15];
}

// ---------------- weight pre-conversion: fp32 -> frag-ordered bf16 hi/lo, x TSCALE ----------------
__global__ __launch_bounds__(256) void wconv(
    const float* __restrict__ msg_w1, const float* __restrict__ msg_w2,
    const float* __restrict__ upd_w1, const float* __restrict__ upd_w2) {
  const int t = blockIdx.x * 256 + threadIdx.x;
  const float* src;
  unsigned short *dh, *dl;
  if (t < 16384) {                               // W1 (Phase C): [l][tile][ks][lane][8]
    const int lane = t & 63, ks = (t >> 6) & 3, tile = (t >> 8) & 15, l = t >> 12;
    src = msg_w1 + l * EMB * W1C + (((tile & 7) << 4) + (lane & 15)) * W1C
        + (tile >> 3) * EMB + ks * 32 + ((lane >> 4) << 3);
    dh = g_wC_h + t * 8; dl = g_wC_l + t * 8;
  } else if (t < 24576) {                        // W2 (Phase D): [l][ct][ks][lane][8]
    const int r = t - 16384;
    const int lane = r & 63, ks = (r >> 6) & 3, ct = (r >> 8) & 7, l = r >> 11;
    src = msg_w2 + l * EMB * EMB + ((ct << 4) + (lane & 15)) * EMB + ks * 32 + ((lane >> 4) << 3);
    dh = g_wD_h + r * 8; dl = g_wD_l + r * 8;
  } else if (t < 40960) {                        // UW1 (E1): [l][ct][ks(8)][lane][8]
    const int r = t - 24576;
    const int lane = r & 63, ks = (r >> 6) & 7, ct = (r >> 9) & 7, l = r >> 12;
    src = upd_w1 + l * EMB * 2 * EMB + ((ct << 4) + (lane & 15)) * 2 * EMB + ks * 32 + ((lane >> 4) << 3);
    dh = g_wE1_h + r * 8; dl = g_wE1_l + r * 8;
  } else if (t < 49152) {                        // UW2 (E2): [l][ct][ks(4)][lane][8]
    const int r = t - 40960;
    const int lane = r & 63, ks = (r >> 6) & 3, ct = (r >> 8) & 7, l = r >> 11;
    src = upd_w2 + l * EMB * EMB + ((ct << 4) + (lane & 15)) * EMB + ks * 32 + ((lane >> 4) << 3);
    dh = g_wE2_h + r * 8; dl = g_wE2_l + r * 8;
  } else return;
  unsigned short hh[8], ll[8];
  #pragma unroll
  for (int m = 0; m < 8; m++) {
    const float x = src[m] * TSCALE;             // fold tanh 2*log2e pre-scale into weights
    const unsigned short hb = f2bf(x);
    hh[m] = hb;
    ll[m] = f2bf(x - bf2f(hb));
  }
  *(short8*)dh = *(const short8*)hh;
  *(short8*)dl = *(const short8*)ll;
}

__global__ __launch_bounds__(1024)
__attribute__((amdgpu_waves_per_eu(4, 4)))     // 4 waves/EU: 128 total regs/wave (64 arch + 64 AGPR)
void fsd_fused(
    const float* __restrict__ pos, const float* __restrict__ enc,
    const float* __restrict__ pos_emb, const float* __restrict__ na_emb,
    const int* __restrict__ T,
    const float* __restrict__ fc1_w, const float* __restrict__ fc1_b,
    const float* __restrict__ fc2_w, const float* __restrict__ fc2_b,
    const float* __restrict__ lin_w, const float* __restrict__ lin_b,
    const float* __restrict__ msg_w1, const float* __restrict__ msg_b1,
    const float* __restrict__ msg_b2,
    const float* __restrict__ upd_b1, const float* __restrict__ upd_b2,
    float* __restrict__ out)
{
  __shared__ __align__(16) float h32[NN][UPAD];
  __shared__ __align__(16) float u_s[NN][UPAD];     // pos_emb staging; hid32 in E1
  __shared__ __align__(16) float v_s[NN][UPAD];
  __shared__ __align__(16) unsigned short hfH[8][64][8],  hfL[8][64][8];   // h A-frags
  __shared__ __align__(16) unsigned short agfH[8][64][8], agfL[8][64][8];  // aggr A-frags; hid frags in E2
  __shared__ __align__(16) unsigned short w2fH[8][4][64][8], w2fL[8][4][64][8]; // W2 B-frags (64 KB)
  __shared__ float e_s[EMB];
  __shared__ float c5_s[EMB];
  __shared__ float b2m_s[EMB];
  __shared__ float clsU[2][EMB], clsV[2][EMB];
  __shared__ float enc_s[ENCD];
  __shared__ float hidA_s[64];
  __shared__ float posx_s[NN], posy_s[NN];
  __shared__ int   T_s[NN];

  const int b    = blockIdx.x;
  const int tid  = threadIdx.x;
  const int w    = tid >> 6, lane = tid & 63;   // 16 waves
  const int o    = tid & 127, g8 = tid >> 7;    // [0,8): node-group for VALU phases
  const int l15  = lane & 15, l4 = lane >> 4;

  // ---------------- Phase A: decoder_fc -> e_s ----------------
  if (tid < ENCD) enc_s[tid] = enc[b * ENCD + tid];
  if (tid < NN) {
    posx_s[tid] = pos[(b * NN + tid) * 2 + 0];
    posy_s[tid] = pos[(b * NN + tid) * 2 + 1];
    T_s[tid]    = T[b * NN + tid];
  }
  __syncthreads();
  if (tid < 64) {
    float a = fc1_b[tid];
    const float* wr = fc1_w + tid * ENCD;
    #pragma unroll 8
    for (int k = 0; k < ENCD; k++) a += enc_s[k] * wr[k];
    hidA_s[tid] = fast_tanh(a);
  }
  __syncthreads();
  if (tid < EMB) {
    float a = fc2_b[tid];
    const float* wr = fc2_w + tid * 64;
    #pragma unroll 8
    for (int k = 0; k < 64; k++) a += hidA_s[k] * wr[k];
    e_s[tid] = a;
  }
  float* pe_s = &u_s[0][0];
  for (int idx = tid; idx < NN * PEMB; idx += 1024)
    pe_s[idx] = pos_emb[b * NN * PEMB + idx];
  __syncthreads();

  // ---------------- Phase B: h0 = x @ lin_w^T + lin_b (unscaled, no tanh) ----------------
  {
    const float nav = na_emb[b];
    const float* wr = lin_w + o * IND;
    float ebias = lin_b[o] + nav * wr[PEMB];
    #pragma unroll 8
    for (int k = 0; k < EMB; k++) ebias += e_s[k] * wr[65 + k];
    float acc[4];
    #pragma unroll
    for (int n = 0; n < 4; n++) acc[n] = ebias;
    for (int kc = 0; kc < PEMB; kc += 16) {
      float wreg[16];
      #pragma unroll
      for (int q = 0; q < 16; q++) wreg[q] = wr[kc + q];
      #pragma unroll
      for (int n = 0; n < 4; n++)
        acc[n] += dot16_lds(&pe_s[(g8 + 8 * n) * PEMB + kc], wreg);
    }
    __syncthreads();   // pe reads done before u_s reuse
    #pragma unroll
    for (int n = 0; n < 4; n++) h32[g8 + 8 * n][o] = acc[n];
  }
  __syncthreads();
  if (w < 8) cvt_plane(h32, hfH, hfL, w, lane);
  __syncthreads();

  // ---------------- Layer loop ----------------
  for (int l = 0; l < NLAY; l++) {
    const float* b1  = msg_b1 + l * EMB;
    const float* b2  = msg_b2 + l * EMB;
    const float* ub1 = upd_b1 + l * EMB;
    const float* ub2 = upd_b2 + l * EMB;
    const float* w1  = msg_w1 + l * EMB * W1C;   // c5/cls columns only

    // ---- stage (all tanh-input tables PRE-SCALED by TSCALE) ----
    if (tid < EMB) { c5_s[tid] = w1[tid * W1C + 260] * TSCALE; b2m_s[tid] = b2[tid] * TSCALE; }
    {
      const int c = (tid >> 7) & 1, oo = tid & 127;
      if (tid < 256)      clsU[c][oo] = (b1[oo] + w1[oo * W1C + 258 + c]) * TSCALE;
      else if (tid < 512) clsV[c][oo] = w1[oo * W1C + 256 + c] * TSCALE;
    }
    {
      const unsigned short* sH = g_wD_h + l * 16384;
      const unsigned short* sL = g_wD_l + l * 16384;
      unsigned short* dH = &w2fH[0][0][0][0];
      unsigned short* dL = &w2fL[0][0][0][0];
      for (int idx = tid; idx < 2048; idx += 1024) {
        *(short8*)(dH + idx * 8) = *(const short8*)(sH + idx * 8);
        *(short8*)(dL + idx * 8) = *(const short8*)(sL + idx * 8);
      }
    }
    __syncthreads();   // (1) tables + w2f ready, h-frags ready

    // ---- Phase C: u,v = h @ W1parts^T via MFMA (outputs scaled); wave w owns col-tile w ----
    {
      const int part = w >> 3;                   // 0 -> u, 1 -> v
      const int col  = ((w & 7) << 4) + l15;
      floatx4 acc0 = {0.f,0.f,0.f,0.f}, acc1 = {0.f,0.f,0.f,0.f};
      #pragma unroll
      for (int ks = 0; ks < 4; ks++) {
        const int idx = (((l * 16 + w) * 4 + ks) * 64 + lane) * 8;
        const short8 bh = *(const short8*)(g_wC_h + idx);
        const short8 bl = *(const short8*)(g_wC_l + idx);
        const short8 ah0 = *(const short8*)&hfH[ks*2+0][lane][0];
        const short8 al0 = *(const short8*)&hfL[ks*2+0][lane][0];
        const short8 ah1 = *(const short8*)&hfH[ks*2+1][lane][0];
        const short8 al1 = *(const short8*)&hfL[ks*2+1][lane][0];
        acc0 = mfma3(ah0, al0, bh, bl, acc0);
        acc1 = mfma3(ah1, al1, bh, bl, acc1);
      }
      float (*dst)[UPAD] = part ? v_s : u_s;
      const float (*tab)[EMB] = part ? clsV : clsU;
      #pragma unroll
      for (int q = 0; q < 4; q++) {
        const int r0 = (l4 << 2) + q;
        const int r1 = r0 + 16;
        dst[r0][col] = acc0[q] + tab[T_s[r0]][col];
        dst[r1][col] = acc1[q] + tab[T_s[r1]][col];
      }
    }
    __syncthreads();   // (2) u,v ready

    // ---- Phase D: wave w owns dst nodes 2w, 2w+1 sequentially; BOTH jt half-planes
    //      accumulated together (64 AGPRs) so each W2 B-frag is read ONCE per (ii,q).
    //      sched_group_barrier pins (1 ds_read : 2 MFMA) so B live-range stays ~1 read
    //      (r11's spill: all 16 B-reads hoisted = 64 arch regs). ----
    {
      const int j0 = l15, j1 = l15 + 16;
      #pragma unroll 1
      for (int ii = 0; ii < 2; ii++) {
        const int i = (w << 1) + ii;
        const float pix = posx_s[i], piy = posy_s[i];
        float dxx = posx_s[j0] - pix, dyy = posy_s[j0] - piy;
        const float d0 = sqrtf(dxx * dxx + dyy * dyy);
        dxx = posx_s[j1] - pix; dyy = posy_s[j1] - piy;
        const float d1 = sqrtf(dxx * dxx + dyy * dyy);

        floatx4 acc0[8], acc1[8];
        #pragma unroll
        for (int ct = 0; ct < 8; ct++) {
          acc0[ct] = (floatx4){0.f,0.f,0.f,0.f};
          acc1[ct] = (floatx4){0.f,0.f,0.f,0.f};
        }

        #pragma unroll 1
        for (int q = 0; q < 4; q++) {            // k-range q*32 + l4*8
          const int k8 = (q << 5) + (l4 << 3);
          unsigned w0[4], w1r[4];
          build2q(*(const float4*)&u_s[i][k8],     *(const float4*)&v_s[j0][k8],
                  *(const float4*)&v_s[j1][k8],    *(const float4*)&c5_s[k8],
                  d0, d1, &w0[0], &w1r[0]);
          build2q(*(const float4*)&u_s[i][k8 + 4], *(const float4*)&v_s[j0][k8 + 4],
                  *(const float4*)&v_s[j1][k8 + 4],*(const float4*)&c5_s[k8 + 4],
                  d0, d1, &w0[2], &w1r[2]);
          uint4 p0 = make_uint4(w0[0], w0[1], w0[2], w0[3]);
          uint4 p1 = make_uint4(w1r[0], w1r[1], w1r[2], w1r[3]);
          const short8 aF0 = *(short8*)&p0;
          const short8 aF1 = *(short8*)&p1;
          __builtin_amdgcn_sched_barrier(0);     // builds stay above
          #pragma unroll
          for (int ct = 0; ct < 8; ct++) {
            const short8 bl = *(const short8*)&w2fL[ct][q][lane][0];
            acc0[ct] = __builtin_amdgcn_mfma_f32_16x16x32_bf16(aF0, bl, acc0[ct], 0, 0, 0);
            acc1[ct] = __builtin_amdgcn_mfma_f32_16x16x32_bf16(aF1, bl, acc1[ct], 0, 0, 0);
            const short8 bh = *(const short8*)&w2fH[ct][q][lane][0];
            acc0[ct] = __builtin_amdgcn_mfma_f32_16x16x32_bf16(aF0, bh, acc0[ct], 0, 0, 0);
            acc1[ct] = __builtin_amdgcn_mfma_f32_16x16x32_bf16(aF1, bh, acc1[ct], 0, 0, 0);
          }
          // pin: per B-frag, 1 DS_READ then its 2 MFMAs -> <=1 read in flight
          #pragma unroll
          for (int g = 0; g < 16; g++) {
            __builtin_amdgcn_sched_group_barrier(0x100, 1, 0);  // DS_READ x1
            __builtin_amdgcn_sched_group_barrier(0x008, 2, 0);  // MFMA   x2
          }
          __builtin_amdgcn_sched_barrier(0);     // epilogue/next-iter stays below
        }

        // epilogue: m = tanh2(C + b2s), aggregate over all 32 j, scatter to agf
        #pragma unroll
        for (int ct = 0; ct < 8; ct++) {
          const float b2c = b2m_s[(ct << 4) + l15];
          float p = 0.f;
          #pragma unroll
          for (int q = 0; q < 4; q++)
            p += tanh2(acc0[ct][q] + b2c) + tanh2(acc1[ct][q] + b2c);
          p += __shfl_xor(p, 16);
          p += __shfl_xor(p, 32);
          if (lane < 16) {
            const int c     = (ct << 4) + l15;
            const int plane = ((c >> 5) << 1) + (i >> 4);
            const int slot  = (i & 15) + (((c >> 3) & 3) << 4);
            const int elem  = c & 7;
            const unsigned short hb = f2bf(p);
            agfH[plane][slot][elem] = hb;
            agfL[plane][slot][elem] = f2bf(p - bf2f(hb));
          }
        }
      }
    }
    __syncthreads();   // (3) agf complete; u_s free

    // ---- Phase E1: hid = tanh2([h|aggr] @ uw1s^T + ub1*S) -> u_s.
    //      wave w: col-tile ct = w&7, row-half jt = w>>3 ----
    {
      const int ct = w & 7, jt = w >> 3;
      const int col = (ct << 4) + l15;
      const float bo = ub1[col] * TSCALE;
      floatx4 acc = {0.f,0.f,0.f,0.f};
      #pragma unroll
      for (int ks = 0; ks < 8; ks++) {
        const int idx = (((l * 8 + ct) * 8 + ks) * 64 + lane) * 8;
        const short8 bh = *(const short8*)(g_wE1_h + idx);
        const short8 bl = *(const short8*)(g_wE1_l + idx);
        short8 ah, al;
        if (ks < 4) {
          ah = *(const short8*)&hfH[ks*2+jt][lane][0];
          al = *(const short8*)&hfL[ks*2+jt][lane][0];
        } else {
          ah = *(const short8*)&agfH[(ks-4)*2+jt][lane][0];
          al = *(const short8*)&agfL[(ks-4)*2+jt][lane][0];
        }
        acc = mfma3(ah, al, bh, bl, acc);
      }
      #pragma unroll
      for (int q = 0; q < 4; q++) {
        const int r = (jt << 4) + (l4 << 2) + q;
        u_s[r][col] = tanh2(acc[q] + bo);        // u_s reused as hid32 (unscaled output)
      }
    }
    __syncthreads();   // (4) hid32 ready AND all agf/hf reads done

    if (w < 8) cvt_plane(u_s, agfH, agfL, w, lane);   // hid frags into agf
    __syncthreads();   // (5)

    // ---- Phase E2: h += tanh2(hid @ uw2s^T + ub2*S); same (ct, jt) split ----
    {
      const int ct = w & 7, jt = w >> 3;
      const int col = (ct << 4) + l15;
      const float bo = ub2[col] * TSCALE;
      floatx4 acc = {0.f,0.f,0.f,0.f};
      #pragma unroll
      for (int ks = 0; ks < 4; ks++) {
        const int idx = (((l * 8 + ct) * 4 + ks) * 64 + lane) * 8;
        const short8 bh = *(const short8*)(g_wE2_h + idx);
        const short8 bl = *(const short8*)(g_wE2_l + idx);
        const short8 ah = *(const short8*)&agfH[ks*2+jt][lane][0];
        const short8 al = *(const short8*)&agfL[ks*2+jt][lane][0];
        acc = mfma3(ah, al, bh, bl, acc);
      }
      #pragma unroll
      for (int q = 0; q < 4; q++) {
        const int r = (jt << 4) + (l4 << 2) + q;
        h32[r][col] += tanh2(acc[q] + bo);
      }
    }
    __syncthreads();   // (6) h updated

    if (l + 1 < NLAY) {
      if (w < 8) cvt_plane(h32, hfH, hfL, w, lane);
      __syncthreads();
    }
  }

  // ---------------- write out ----------------
  for (int idx = tid; idx < NN * EMB; idx += 1024)
    out[b * NN * EMB + idx] = h32[idx >> 7][idx & 127];
}

extern "C" void kernel_launch(void* const* d_in, const int* in_sizes, int n_in,
                              void* d_out, int out_size, void* d_ws, size_t ws_size,
                              hipStream_t stream) {
  const float* pos     = (const float*)d_in[0];
  const float* enc     = (const float*)d_in[1];
  const float* pos_emb = (const float*)d_in[2];
  const float* na_emb  = (const float*)d_in[3];
  const int*   T       = (const int*)d_in[4];
  // d_in[5] = num_agents (compile-time 32)
  const float* fc1_w = (const float*)d_in[6];
  const float* fc1_b = (const float*)d_in[7];
  const float* fc2_w = (const float*)d_in[8];
  const float* fc2_b = (const float*)d_in[9];
  const float* lin_w = (const float*)d_in[10];
  const float* lin_b = (const float*)d_in[11];
  const float* msg_w1 = (const float*)d_in[12];
  const float* msg_b1 = (const float*)d_in[13];
  const float* msg_w2 = (const float*)d_in[14];
  const float* msg_b2 = (const float*)d_in[15];
  const float* upd_w1 = (const float*)d_in[16];
  const float* upd_b1 = (const float*)d_in[17];
  const float* upd_w2 = (const float*)d_in[18];
  const float* upd_b2 = (const float*)d_in[19];

  wconv<<<192, 256, 0, stream>>>(msg_w1, msg_w2, upd_w1, upd_w2);
  fsd_fused<<<256, 1024, 0, stream>>>(pos, enc, pos_emb, na_emb, T,
      fc1_w, fc1_b, fc2_w, fc2_b, lin_w, lin_b,
      msg_w1, msg_b1, msg_b2, upd_b1, upd_b2,
      (float*)d_out);
}

// Round 13
// 161.733 us; speedup vs baseline: 1.1128x; 1.1128x over previous
//
#include <hip/hip_runtime.h>

#define NN   32
#define EMB  128
#define PEMB 64
#define ENCD 256
#define NLAY 4
#define W1C  261   // 2*EMB + 2*NCLS + 1
#define IND  193   // PEMB + 1 + EMB
#define UPAD 132   // padded row (floats): +16B breaks bank patterns
#define TSCALE 2.885390081777927f   // 2*log2(e): tanh(x) = 1 - 2/(exp2(TSCALE*x)+1)

typedef __attribute__((ext_vector_type(8))) short short8;
typedef __attribute__((ext_vector_type(4))) float floatx4;
typedef __attribute__((ext_vector_type(16))) float floatx16;

// ---- pre-converted weight fragments (bf16 hi/lo, PRE-SCALED by TSCALE), filled by wconv ----
__device__ unsigned short g_wC_h[16384 * 8], g_wC_l[16384 * 8];   // W1 frags (16x16x32)
__device__ unsigned short g_wD_h[8192 * 8],  g_wD_l[8192 * 8];    // W2 frags (32x32x16!)
__device__ unsigned short g_wE1_h[16384 * 8], g_wE1_l[16384 * 8]; // UW1 frags
__device__ unsigned short g_wE2_h[8192 * 8],  g_wE2_l[8192 * 8];  // UW2 frags

// tanh(x) = 1 - 2/(exp(2x)+1)   (Phase A only; unscaled weights there)
__device__ __forceinline__ float fast_tanh(float x) {
  float e = __expf(2.0f * x);
  return 1.0f - __fdividef(2.0f, e + 1.0f);
}
// tanh from PRE-SCALED input s = 2*log2(e)*x : exp2 + add + rcp + fma
__device__ __forceinline__ float tanh2(float s) {
  float e;
  asm("v_exp_f32 %0, %1" : "=v"(e) : "v"(s));
  const float ep1 = e + 1.0f;
  float r;
  asm("v_rcp_f32 %0, %1" : "=v"(r) : "v"(ep1));
  return __builtin_fmaf(-2.0f, r, 1.0f);
}
// fp32 -> bf16 RNE
__device__ __forceinline__ unsigned short f2bf(float x) {
  unsigned u = __float_as_uint(x);
  return (unsigned short)((u + 0x7fffu + ((u >> 16) & 1u)) >> 16);
}
__device__ __forceinline__ float bf2f(unsigned short h) {
  return __uint_as_float(((unsigned)h) << 16);
}
// hw packed convert: dst.lo16 = bf16(a), dst.hi16 = bf16(b)
__device__ __forceinline__ unsigned cvtpk(float a, float b) {
  unsigned r;
  asm("v_cvt_pk_bf16_f32 %0, %1, %2" : "=v"(r) : "v"(a), "v"(b));
  return r;
}

// A*B with A,B split hi/lo bf16 (drop lo*lo): 3 MFMAs (16x16x32)
__device__ __forceinline__ floatx4 mfma3(short8 ah, short8 al, short8 bh, short8 bl, floatx4 acc) {
  acc = __builtin_amdgcn_mfma_f32_16x16x32_bf16(ah, bh, acc, 0, 0, 0);
  acc = __builtin_amdgcn_mfma_f32_16x16x32_bf16(al, bh, acc, 0, 0, 0);
  acc = __builtin_amdgcn_mfma_f32_16x16x32_bf16(ah, bl, acc, 0, 0, 0);
  return acc;
}

// one fragment plane p (jt=p&1, kstep=p>>1) from fp32 [NN][UPAD] -> hi/lo frag LDS (16x16x32 A)
__device__ __forceinline__ void cvt_plane(const float (*src)[UPAD],
                                          unsigned short (*dH)[64][8],
                                          unsigned short (*dL)[64][8],
                                          int p, int lane) {
  const int row  = (lane & 15) + ((p & 1) << 4);
  const int koff = ((p >> 1) << 5) + ((lane >> 4) << 3);
  float x[8];
  *(float4*)&x[0] = *(const float4*)&src[row][koff];
  *(float4*)&x[4] = *(const float4*)&src[row][koff + 4];
  unsigned h[4], lo[4];
  #pragma unroll
  for (int q = 0; q < 4; q++) {
    h[q] = cvtpk(x[2*q], x[2*q+1]);
    const float r0 = x[2*q]   - __uint_as_float(h[q] << 16);
    const float r1 = x[2*q+1] - __uint_as_float(h[q] & 0xffff0000u);
    lo[q] = cvtpk(r0, r1);
  }
  *(uint4*)&dH[p][lane][0] = make_uint4(h[0], h[1], h[2], h[3]);
  *(uint4*)&dL[p][lane][0] = make_uint4(lo[0], lo[1], lo[2], lo[3]);
}

// 32x32x16 A-frag build: 8 consecutive k of tanh2(u+v+d*c5), bf16-packed
__device__ __forceinline__ short8 build_t32(const float* us, const float* vs,
                                            const float* cs, float d) {
  const float4 u0 = *(const float4*)us, u1 = *(const float4*)(us + 4);
  const float4 v0 = *(const float4*)vs, v1 = *(const float4*)(vs + 4);
  const float4 c0 = *(const float4*)cs, c1 = *(const float4*)(cs + 4);
  const float t0 = tanh2(u0.x + v0.x + d * c0.x);
  const float t1 = tanh2(u0.y + v0.y + d * c0.y);
  const float t2 = tanh2(u0.z + v0.z + d * c0.z);
  const float t3 = tanh2(u0.w + v0.w + d * c0.w);
  const float t4 = tanh2(u1.x + v1.x + d * c1.x);
  const float t5 = tanh2(u1.y + v1.y + d * c1.y);
  const float t6 = tanh2(u1.z + v1.z + d * c1.z);
  const float t7 = tanh2(u1.w + v1.w + d * c1.w);
  uint4 p = make_uint4(cvtpk(t0, t1), cvtpk(t2, t3), cvtpk(t4, t5), cvtpk(t6, t7));
  return *(short8*)&p;
}

__device__ __forceinline__ float dot16_lds(const float* base, const float* wreg) {
  const float4 a = *(const float4*)(base);
  const float4 b = *(const float4*)(base + 4);
  const float4 c = *(const float4*)(base + 8);
  const float4 d = *(const float4*)(base + 12);
  return a.x*wreg[0] + a.y*wreg[1] + a.z*wreg[2]  + a.w*wreg[3]
       + b.x*wreg[4] + b.y*wreg[5] + b.z*wreg[6]  + b.w*wreg[7]
       + c.x*wreg[8] + c.y*wreg[9] + c.z*wreg[10] + c.w*wreg[11]
       + d.x*wreg[12]+ d.y*wreg[13]+ d.z*wreg[14] + d.w*wreg[15];
}

// ---------------- weight pre-conversion: fp32 -> frag-ordered bf16 hi/lo, x TSCALE ----------------
__global__ __launch_bounds__(256) void wconv(
    const float* __restrict__ msg_w1, const float* __restrict__ msg_w2,
    const float* __restrict__ upd_w1, const float* __restrict__ upd_w2) {
  const int t = blockIdx.x * 256 + threadIdx.x;
  const float* src;
  unsigned short *dh, *dl;
  if (t < 16384) {                               // W1 (Phase C): [l][tile][ks][lane][8]
    const int lane = t & 63, ks = (t >> 6) & 3, tile = (t >> 8) & 15, l = t >> 12;
    src = msg_w1 + l * EMB * W1C + (((tile & 7) << 4) + (lane & 15)) * W1C
        + (tile >> 3) * EMB + ks * 32 + ((lane >> 4) << 3);
    dh = g_wC_h + t * 8; dl = g_wC_l + t * 8;
  } else if (t < 24576) {                        // W2 (Phase D, 32x32x16): [l][nt(4)][kt(8)][lane][8]
    const int r = t - 16384;
    const int lane = r & 63, kt = (r >> 6) & 7, nt = (r >> 9) & 3, l = r >> 11;
    src = msg_w2 + l * EMB * EMB + ((nt << 5) + (lane & 31)) * EMB + (kt << 4) + ((lane >> 5) << 3);
    dh = g_wD_h + r * 8; dl = g_wD_l + r * 8;
  } else if (t < 40960) {                        // UW1 (E1): [l][ct][ks(8)][lane][8]
    const int r = t - 24576;
    const int lane = r & 63, ks = (r >> 6) & 7, ct = (r >> 9) & 7, l = r >> 12;
    src = upd_w1 + l * EMB * 2 * EMB + ((ct << 4) + (lane & 15)) * 2 * EMB + ks * 32 + ((lane >> 4) << 3);
    dh = g_wE1_h + r * 8; dl = g_wE1_l + r * 8;
  } else if (t < 49152) {                        // UW2 (E2): [l][ct][ks(4)][lane][8]
    const int r = t - 40960;
    const int lane = r & 63, ks = (r >> 6) & 3, ct = (r >> 8) & 7, l = r >> 11;
    src = upd_w2 + l * EMB * EMB + ((ct << 4) + (lane & 15)) * EMB + ks * 32 + ((lane >> 4) << 3);
    dh = g_wE2_h + r * 8; dl = g_wE2_l + r * 8;
  } else return;
  unsigned short hh[8], ll[8];
  #pragma unroll
  for (int m = 0; m < 8; m++) {
    const float x = src[m] * TSCALE;             // fold tanh 2*log2e pre-scale into weights
    const unsigned short hb = f2bf(x);
    hh[m] = hb;
    ll[m] = f2bf(x - bf2f(hb));
  }
  *(short8*)dh = *(const short8*)hh;
  *(short8*)dl = *(const short8*)ll;
}

__global__ __launch_bounds__(1024)
__attribute__((amdgpu_waves_per_eu(4, 4)))     // 4 waves/EU: 128 total regs/wave (64 arch + 64 AGPR)
void fsd_fused(
    const float* __restrict__ pos, const float* __restrict__ enc,
    const float* __restrict__ pos_emb, const float* __restrict__ na_emb,
    const int* __restrict__ T,
    const float* __restrict__ fc1_w, const float* __restrict__ fc1_b,
    const float* __restrict__ fc2_w, const float* __restrict__ fc2_b,
    const float* __restrict__ lin_w, const float* __restrict__ lin_b,
    const float* __restrict__ msg_w1, const float* __restrict__ msg_b1,
    const float* __restrict__ msg_b2,
    const float* __restrict__ upd_b1, const float* __restrict__ upd_b2,
    float* __restrict__ out)
{
  __shared__ __align__(16) float h32[NN][UPAD];
  __shared__ __align__(16) float u_s[NN][UPAD];     // pos_emb staging; hid32 in E1
  __shared__ __align__(16) float v_s[NN][UPAD];
  __shared__ __align__(16) unsigned short hfH[8][64][8],  hfL[8][64][8];   // h A-frags
  __shared__ __align__(16) unsigned short agfH[8][64][8], agfL[8][64][8];  // aggr A-frags; hid frags in E2
  __shared__ __align__(16) unsigned short w2fH[4][8][64][8], w2fL[4][8][64][8]; // W2 B-frags 32x32 (64 KB)
  __shared__ float e_s[EMB];
  __shared__ float c5_s[EMB];
  __shared__ float b2m_s[EMB];
  __shared__ float clsU[2][EMB], clsV[2][EMB];
  __shared__ float enc_s[ENCD];
  __shared__ float hidA_s[64];
  __shared__ float posx_s[NN], posy_s[NN];
  __shared__ int   T_s[NN];

  const int b    = blockIdx.x;
  const int tid  = threadIdx.x;
  const int w    = tid >> 6, lane = tid & 63;   // 16 waves
  const int o    = tid & 127, g8 = tid >> 7;    // [0,8): node-group for VALU phases
  const int l15  = lane & 15, l4 = lane >> 4;

  // ---------------- Phase A: decoder_fc -> e_s ----------------
  if (tid < ENCD) enc_s[tid] = enc[b * ENCD + tid];
  if (tid < NN) {
    posx_s[tid] = pos[(b * NN + tid) * 2 + 0];
    posy_s[tid] = pos[(b * NN + tid) * 2 + 1];
    T_s[tid]    = T[b * NN + tid];
  }
  __syncthreads();
  if (tid < 64) {
    float a = fc1_b[tid];
    const float* wr = fc1_w + tid * ENCD;
    #pragma unroll 8
    for (int k = 0; k < ENCD; k++) a += enc_s[k] * wr[k];
    hidA_s[tid] = fast_tanh(a);
  }
  __syncthreads();
  if (tid < EMB) {
    float a = fc2_b[tid];
    const float* wr = fc2_w + tid * 64;
    #pragma unroll 8
    for (int k = 0; k < 64; k++) a += hidA_s[k] * wr[k];
    e_s[tid] = a;
  }
  float* pe_s = &u_s[0][0];
  for (int idx = tid; idx < NN * PEMB; idx += 1024)
    pe_s[idx] = pos_emb[b * NN * PEMB + idx];
  __syncthreads();

  // ---------------- Phase B: h0 = x @ lin_w^T + lin_b (unscaled, no tanh) ----------------
  {
    const float nav = na_emb[b];
    const float* wr = lin_w + o * IND;
    float ebias = lin_b[o] + nav * wr[PEMB];
    #pragma unroll 8
    for (int k = 0; k < EMB; k++) ebias += e_s[k] * wr[65 + k];
    float acc[4];
    #pragma unroll
    for (int n = 0; n < 4; n++) acc[n] = ebias;
    for (int kc = 0; kc < PEMB; kc += 16) {
      float wreg[16];
      #pragma unroll
      for (int q = 0; q < 16; q++) wreg[q] = wr[kc + q];
      #pragma unroll
      for (int n = 0; n < 4; n++)
        acc[n] += dot16_lds(&pe_s[(g8 + 8 * n) * PEMB + kc], wreg);
    }
    __syncthreads();   // pe reads done before u_s reuse
    #pragma unroll
    for (int n = 0; n < 4; n++) h32[g8 + 8 * n][o] = acc[n];
  }
  __syncthreads();
  if (w < 8) cvt_plane(h32, hfH, hfL, w, lane);
  __syncthreads();

  // ---------------- Layer loop ----------------
  for (int l = 0; l < NLAY; l++) {
    const float* b1  = msg_b1 + l * EMB;
    const float* b2  = msg_b2 + l * EMB;
    const float* ub1 = upd_b1 + l * EMB;
    const float* ub2 = upd_b2 + l * EMB;
    const float* w1  = msg_w1 + l * EMB * W1C;   // c5/cls columns only

    // ---- stage (all tanh-input tables PRE-SCALED by TSCALE) ----
    if (tid < EMB) { c5_s[tid] = w1[tid * W1C + 260] * TSCALE; b2m_s[tid] = b2[tid] * TSCALE; }
    {
      const int c = (tid >> 7) & 1, oo = tid & 127;
      if (tid < 256)      clsU[c][oo] = (b1[oo] + w1[oo * W1C + 258 + c]) * TSCALE;
      else if (tid < 512) clsV[c][oo] = w1[oo * W1C + 256 + c] * TSCALE;
    }
    {
      const unsigned short* sH = g_wD_h + l * 16384;
      const unsigned short* sL = g_wD_l + l * 16384;
      unsigned short* dH = &w2fH[0][0][0][0];
      unsigned short* dL = &w2fL[0][0][0][0];
      for (int idx = tid; idx < 2048; idx += 1024) {
        *(short8*)(dH + idx * 8) = *(const short8*)(sH + idx * 8);
        *(short8*)(dL + idx * 8) = *(const short8*)(sL + idx * 8);
      }
    }
    __syncthreads();   // (1) tables + w2f ready, h-frags ready

    // ---- Phase C: u,v = h @ W1parts^T via MFMA (outputs scaled); wave w owns col-tile w ----
    {
      const int part = w >> 3;                   // 0 -> u, 1 -> v
      const int col  = ((w & 7) << 4) + l15;
      floatx4 acc0 = {0.f,0.f,0.f,0.f}, acc1 = {0.f,0.f,0.f,0.f};
      #pragma unroll
      for (int ks = 0; ks < 4; ks++) {
        const int idx = (((l * 16 + w) * 4 + ks) * 64 + lane) * 8;
        const short8 bh = *(const short8*)(g_wC_h + idx);
        const short8 bl = *(const short8*)(g_wC_l + idx);
        const short8 ah0 = *(const short8*)&hfH[ks*2+0][lane][0];
        const short8 al0 = *(const short8*)&hfL[ks*2+0][lane][0];
        const short8 ah1 = *(const short8*)&hfH[ks*2+1][lane][0];
        const short8 al1 = *(const short8*)&hfL[ks*2+1][lane][0];
        acc0 = mfma3(ah0, al0, bh, bl, acc0);
        acc1 = mfma3(ah1, al1, bh, bl, acc1);
      }
      float (*dst)[UPAD] = part ? v_s : u_s;
      const float (*tab)[EMB] = part ? clsV : clsU;
      #pragma unroll
      for (int q = 0; q < 4; q++) {
        const int r0 = (l4 << 2) + q;
        const int r1 = r0 + 16;
        dst[r0][col] = acc0[q] + tab[T_s[r0]][col];
        dst[r1][col] = acc1[q] + tab[T_s[r1]][col];
      }
    }
    __syncthreads();   // (2) u,v ready

    // ---- Phase D (32x32x16): wave w owns dst nodes 2w, 2w+1 sequentially.
    //      M=32 spans ALL source nodes -> each W2 B-frag read ONCE per node;
    //      acc = one f32x16 (16 AGPRs) per nt; 8 A-frags persistent. ----
    {
      const int j32 = lane & 31;          // A row = source node
      const int khi = (lane >> 5) << 3;   // k-subrange within frag
      const float pjx = posx_s[j32], pjy = posy_s[j32];
      #pragma unroll 1
      for (int ii = 0; ii < 2; ii++) {
        const int i = (w << 1) + ii;
        const float dxx = pjx - posx_s[i], dyy = pjy - posy_s[i];
        const float d = sqrtf(dxx * dxx + dyy * dyy);
        const short8 aF0 = build_t32(&u_s[i][  0 + khi], &v_s[j32][  0 + khi], &c5_s[  0 + khi], d);
        const short8 aF1 = build_t32(&u_s[i][ 16 + khi], &v_s[j32][ 16 + khi], &c5_s[ 16 + khi], d);
        const short8 aF2 = build_t32(&u_s[i][ 32 + khi], &v_s[j32][ 32 + khi], &c5_s[ 32 + khi], d);
        const short8 aF3 = build_t32(&u_s[i][ 48 + khi], &v_s[j32][ 48 + khi], &c5_s[ 48 + khi], d);
        const short8 aF4 = build_t32(&u_s[i][ 64 + khi], &v_s[j32][ 64 + khi], &c5_s[ 64 + khi], d);
        const short8 aF5 = build_t32(&u_s[i][ 80 + khi], &v_s[j32][ 80 + khi], &c5_s[ 80 + khi], d);
        const short8 aF6 = build_t32(&u_s[i][ 96 + khi], &v_s[j32][ 96 + khi], &c5_s[ 96 + khi], d);
        const short8 aF7 = build_t32(&u_s[i][112 + khi], &v_s[j32][112 + khi], &c5_s[112 + khi], d);

        #pragma unroll 1
        for (int nt = 0; nt < 4; nt++) {
          floatx16 acc = {0.f,0.f,0.f,0.f,0.f,0.f,0.f,0.f,0.f,0.f,0.f,0.f,0.f,0.f,0.f,0.f};
          #define DSTEP(kt, aF) { \
            const short8 bl_ = *(const short8*)&w2fL[nt][kt][lane][0]; \
            acc = __builtin_amdgcn_mfma_f32_32x32x16_bf16(aF, bl_, acc, 0, 0, 0); \
            const short8 bh_ = *(const short8*)&w2fH[nt][kt][lane][0]; \
            acc = __builtin_amdgcn_mfma_f32_32x32x16_bf16(aF, bh_, acc, 0, 0, 0); }
          DSTEP(0, aF0) DSTEP(1, aF1) DSTEP(2, aF2) DSTEP(3, aF3)
          DSTEP(4, aF4) DSTEP(5, aF5) DSTEP(6, aF6) DSTEP(7, aF7)
          #undef DSTEP
          // pin: 1 DS_READ then its MFMA, x16 -> <=1 B-read in flight (no hoist spill)
          #pragma unroll
          for (int g = 0; g < 16; g++) {
            __builtin_amdgcn_sched_group_barrier(0x100, 1, 0);  // DS_READ x1
            __builtin_amdgcn_sched_group_barrier(0x008, 1, 0);  // MFMA   x1
          }
          __builtin_amdgcn_sched_barrier(0);
          // epilogue: C/D col=lane&31; rows split across reg & lane>>5 -> 16 tanh + xor32
          const int c = (nt << 5) + j32;
          const float b2c = b2m_s[c];
          float p0 = 0.f, p1 = 0.f;
          #pragma unroll
          for (int rr = 0; rr < 16; rr += 2) {
            p0 += tanh2(acc[rr]     + b2c);
            p1 += tanh2(acc[rr + 1] + b2c);
          }
          float p = p0 + p1;
          p += __shfl_xor(p, 32);
          if (lane < 32) {
            const int plane = (nt << 1) + (i >> 4);
            const int slot  = (i & 15) + (((c >> 3) & 3) << 4);
            const int elem  = c & 7;
            const unsigned short hb = f2bf(p);
            agfH[plane][slot][elem] = hb;
            agfL[plane][slot][elem] = f2bf(p - bf2f(hb));
          }
        }
      }
    }
    __syncthreads();   // (3) agf complete; u_s free

    // ---- Phase E1: hid = tanh2([h|aggr] @ uw1s^T + ub1*S) -> u_s.
    //      wave w: col-tile ct = w&7, row-half jt = w>>3 ----
    {
      const int ct = w & 7, jt = w >> 3;
      const int col = (ct << 4) + l15;
      const float bo = ub1[col] * TSCALE;
      floatx4 acc = {0.f,0.f,0.f,0.f};
      #pragma unroll
      for (int ks = 0; ks < 8; ks++) {
        const int idx = (((l * 8 + ct) * 8 + ks) * 64 + lane) * 8;
        const short8 bh = *(const short8*)(g_wE1_h + idx);
        const short8 bl = *(const short8*)(g_wE1_l + idx);
        short8 ah, al;
        if (ks < 4) {
          ah = *(const short8*)&hfH[ks*2+jt][lane][0];
          al = *(const short8*)&hfL[ks*2+jt][lane][0];
        } else {
          ah = *(const short8*)&agfH[(ks-4)*2+jt][lane][0];
          al = *(const short8*)&agfL[(ks-4)*2+jt][lane][0];
        }
        acc = mfma3(ah, al, bh, bl, acc);
      }
      #pragma unroll
      for (int q = 0; q < 4; q++) {
        const int r = (jt << 4) + (l4 << 2) + q;
        u_s[r][col] = tanh2(acc[q] + bo);        // u_s reused as hid32 (unscaled output)
      }
    }
    __syncthreads();   // (4) hid32 ready AND all agf/hf reads done

    if (w < 8) cvt_plane(u_s, agfH, agfL, w, lane);   // hid frags into agf
    __syncthreads();   // (5)

    // ---- Phase E2: h += tanh2(hid @ uw2s^T + ub2*S); same (ct, jt) split ----
    {
      const int ct = w & 7, jt = w >> 3;
      const int col = (ct << 4) + l15;
      const float bo = ub2[col] * TSCALE;
      floatx4 acc = {0.f,0.f,0.f,0.f};
      #pragma unroll
      for (int ks = 0; ks < 4; ks++) {
        const int idx = (((l * 8 + ct) * 4 + ks) * 64 + lane) * 8;
        const short8 bh = *(const short8*)(g_wE2_h + idx);
        const short8 bl = *(const short8*)(g_wE2_l + idx);
        const short8 ah = *(const short8*)&agfH[ks*2+jt][lane][0];
        const short8 al = *(const short8*)&agfL[ks*2+jt][lane][0];
        acc = mfma3(ah, al, bh, bl, acc);
      }
      #pragma unroll
      for (int q = 0; q < 4; q++) {
        const int r = (jt << 4) + (l4 << 2) + q;
        h32[r][col] += tanh2(acc[q] + bo);
      }
    }
    __syncthreads();   // (6) h updated

    if (l + 1 < NLAY) {
      if (w < 8) cvt_plane(h32, hfH, hfL, w, lane);
      __syncthreads();
    }
  }

  // ---------------- write out ----------------
  for (int idx = tid; idx < NN * EMB; idx += 1024)
    out[b * NN * EMB + idx] = h32[idx >> 7][idx & 127];
}

extern "C" void kernel_launch(void* const* d_in, const int* in_sizes, int n_in,
                              void* d_out, int out_size, void* d_ws, size_t ws_size,
                              hipStream_t stream) {
  const float* pos     = (const float*)d_in[0];
  const float* enc     = (const float*)d_in[1];
  const float* pos_emb = (const float*)d_in[2];
  const float* na_emb  = (const float*)d_in[3];
  const int*   T       = (const int*)d_in[4];
  // d_in[5] = num_agents (compile-time 32)
  const float* fc1_w = (const float*)d_in[6];
  const float* fc1_b = (const float*)d_in[7];
  const float* fc2_w = (const float*)d_in[8];
  const float* fc2_b = (const float*)d_in[9];
  const float* lin_w = (const float*)d_in[10];
  const float* lin_b = (const float*)d_in[11];
  const float* msg_w1 = (const float*)d_in[12];
  const float* msg_b1 = (const float*)d_in[13];
  const float* msg_w2 = (const float*)d_in[14];
  const float* msg_b2 = (const float*)d_in[15];
  const float* upd_w1 = (const float*)d_in[16];
  const float* upd_b1 = (const float*)d_in[17];
  const float* upd_w2 = (const float*)d_in[18];
  const float* upd_b2 = (const float*)d_in[19];

  wconv<<<192, 256, 0, stream>>>(msg_w1, msg_w2, upd_w1, upd_w2);
  fsd_fused<<<256, 1024, 0, stream>>>(pos, enc, pos_emb, na_emb, T,
      fc1_w, fc1_b, fc2_w, fc2_b, lin_w, lin_b,
      msg_w1, msg_b1, msg_b2, upd_b1, upd_b2,
      (float*)d_out);
}

// Round 14
// 157.999 us; speedup vs baseline: 1.1391x; 1.0236x over previous
//
#include <hip/hip_runtime.h>

#define NN   32
#define EMB  128
#define PEMB 64
#define ENCD 256
#define NLAY 4
#define W1C  261   // 2*EMB + 2*NCLS + 1
#define IND  193   // PEMB + 1 + EMB
#define UPAD 132   // padded row (floats): +16B breaks bank patterns
#define TSCALE 2.885390081777927f   // 2*log2(e): tanh(x) = 1 - 2/(exp2(TSCALE*x)+1)

typedef __attribute__((ext_vector_type(8))) short short8;
typedef __attribute__((ext_vector_type(4))) float floatx4;
typedef __attribute__((ext_vector_type(16))) float floatx16;

// ---- pre-converted weight fragments (bf16 hi/lo, PRE-SCALED by TSCALE), filled by wconv ----
__device__ unsigned short g_wC_h[16384 * 8], g_wC_l[16384 * 8];   // W1 frags (16x16x32)
__device__ unsigned short g_wD_h[8192 * 8],  g_wD_l[8192 * 8];    // W2 frags (32x32x16)
__device__ unsigned short g_wE1_h[16384 * 8], g_wE1_l[16384 * 8]; // UW1 frags
__device__ unsigned short g_wE2_h[8192 * 8],  g_wE2_l[8192 * 8];  // UW2 frags

// tanh(x) = 1 - 2/(exp(2x)+1)   (Phase A only; unscaled weights there)
__device__ __forceinline__ float fast_tanh(float x) {
  float e = __expf(2.0f * x);
  return 1.0f - __fdividef(2.0f, e + 1.0f);
}
// tanh from PRE-SCALED input s = 2*log2(e)*x : exp2 + add + rcp + fma
__device__ __forceinline__ float tanh2(float s) {
  float e;
  asm("v_exp_f32 %0, %1" : "=v"(e) : "v"(s));
  const float ep1 = e + 1.0f;
  float r;
  asm("v_rcp_f32 %0, %1" : "=v"(r) : "v"(ep1));
  return __builtin_fmaf(-2.0f, r, 1.0f);
}
// fp32 -> bf16 RNE
__device__ __forceinline__ unsigned short f2bf(float x) {
  unsigned u = __float_as_uint(x);
  return (unsigned short)((u + 0x7fffu + ((u >> 16) & 1u)) >> 16);
}
__device__ __forceinline__ float bf2f(unsigned short h) {
  return __uint_as_float(((unsigned)h) << 16);
}
// hw packed convert: dst.lo16 = bf16(a), dst.hi16 = bf16(b)
__device__ __forceinline__ unsigned cvtpk(float a, float b) {
  unsigned r;
  asm("v_cvt_pk_bf16_f32 %0, %1, %2" : "=v"(r) : "v"(a), "v"(b));
  return r;
}

// A*B with A,B split hi/lo bf16 (drop lo*lo): 3 MFMAs (16x16x32)
__device__ __forceinline__ floatx4 mfma3(short8 ah, short8 al, short8 bh, short8 bl, floatx4 acc) {
  acc = __builtin_amdgcn_mfma_f32_16x16x32_bf16(ah, bh, acc, 0, 0, 0);
  acc = __builtin_amdgcn_mfma_f32_16x16x32_bf16(al, bh, acc, 0, 0, 0);
  acc = __builtin_amdgcn_mfma_f32_16x16x32_bf16(ah, bl, acc, 0, 0, 0);
  return acc;
}

// one fragment plane p (jt=p&1, kstep=p>>1) from fp32 [NN][UPAD] -> hi/lo frag LDS (16x16x32 A)
__device__ __forceinline__ void cvt_plane(const float (*src)[UPAD],
                                          unsigned short (*dH)[64][8],
                                          unsigned short (*dL)[64][8],
                                          int p, int lane) {
  const int row  = (lane & 15) + ((p & 1) << 4);
  const int koff = ((p >> 1) << 5) + ((lane >> 4) << 3);
  float x[8];
  *(float4*)&x[0] = *(const float4*)&src[row][koff];
  *(float4*)&x[4] = *(const float4*)&src[row][koff + 4];
  unsigned h[4], lo[4];
  #pragma unroll
  for (int q = 0; q < 4; q++) {
    h[q] = cvtpk(x[2*q], x[2*q+1]);
    const float r0 = x[2*q]   - __uint_as_float(h[q] << 16);
    const float r1 = x[2*q+1] - __uint_as_float(h[q] & 0xffff0000u);
    lo[q] = cvtpk(r0, r1);
  }
  *(uint4*)&dH[p][lane][0] = make_uint4(h[0], h[1], h[2], h[3]);
  *(uint4*)&dL[p][lane][0] = make_uint4(lo[0], lo[1], lo[2], lo[3]);
}

// 32x32x16 A-frag build: 8 consecutive k of tanh2(u+v+d*c5), bf16-packed
__device__ __forceinline__ short8 build_t32(const float* us, const float* vs,
                                            const float* cs, float d) {
  const float4 u0 = *(const float4*)us, u1 = *(const float4*)(us + 4);
  const float4 v0 = *(const float4*)vs, v1 = *(const float4*)(vs + 4);
  const float4 c0 = *(const float4*)cs, c1 = *(const float4*)(cs + 4);
  const float t0 = tanh2(u0.x + v0.x + d * c0.x);
  const float t1 = tanh2(u0.y + v0.y + d * c0.y);
  const float t2 = tanh2(u0.z + v0.z + d * c0.z);
  const float t3 = tanh2(u0.w + v0.w + d * c0.w);
  const float t4 = tanh2(u1.x + v1.x + d * c1.x);
  const float t5 = tanh2(u1.y + v1.y + d * c1.y);
  const float t6 = tanh2(u1.z + v1.z + d * c1.z);
  const float t7 = tanh2(u1.w + v1.w + d * c1.w);
  uint4 p = make_uint4(cvtpk(t0, t1), cvtpk(t2, t3), cvtpk(t4, t5), cvtpk(t6, t7));
  return *(short8*)&p;
}

__device__ __forceinline__ float dot16_lds(const float* base, const float* wreg) {
  const float4 a = *(const float4*)(base);
  const float4 b = *(const float4*)(base + 4);
  const float4 c = *(const float4*)(base + 8);
  const float4 d = *(const float4*)(base + 12);
  return a.x*wreg[0] + a.y*wreg[1] + a.z*wreg[2]  + a.w*wreg[3]
       + b.x*wreg[4] + b.y*wreg[5] + b.z*wreg[6]  + b.w*wreg[7]
       + c.x*wreg[8] + c.y*wreg[9] + c.z*wreg[10] + c.w*wreg[11]
       + d.x*wreg[12]+ d.y*wreg[13]+ d.z*wreg[14] + d.w*wreg[15];
}

// ---------------- weight pre-conversion: fp32 -> frag-ordered bf16 hi/lo, x TSCALE ----------------
__global__ __launch_bounds__(256) void wconv(
    const float* __restrict__ msg_w1, const float* __restrict__ msg_w2,
    const float* __restrict__ upd_w1, const float* __restrict__ upd_w2) {
  const int t = blockIdx.x * 256 + threadIdx.x;
  const float* src;
  unsigned short *dh, *dl;
  if (t < 16384) {                               // W1 (Phase C): [l][tile][ks][lane][8]
    const int lane = t & 63, ks = (t >> 6) & 3, tile = (t >> 8) & 15, l = t >> 12;
    src = msg_w1 + l * EMB * W1C + (((tile & 7) << 4) + (lane & 15)) * W1C
        + (tile >> 3) * EMB + ks * 32 + ((lane >> 4) << 3);
    dh = g_wC_h + t * 8; dl = g_wC_l + t * 8;
  } else if (t < 24576) {                        // W2 (Phase D, 32x32x16): [l][nt(4)][kt(8)][lane][8]
    const int r = t - 16384;
    const int lane = r & 63, kt = (r >> 6) & 7, nt = (r >> 9) & 3, l = r >> 11;
    src = msg_w2 + l * EMB * EMB + ((nt << 5) + (lane & 31)) * EMB + (kt << 4) + ((lane >> 5) << 3);
    dh = g_wD_h + r * 8; dl = g_wD_l + r * 8;
  } else if (t < 40960) {                        // UW1 (E1): [l][ct][ks(8)][lane][8]
    const int r = t - 24576;
    const int lane = r & 63, ks = (r >> 6) & 7, ct = (r >> 9) & 7, l = r >> 12;
    src = upd_w1 + l * EMB * 2 * EMB + ((ct << 4) + (lane & 15)) * 2 * EMB + ks * 32 + ((lane >> 4) << 3);
    dh = g_wE1_h + r * 8; dl = g_wE1_l + r * 8;
  } else if (t < 49152) {                        // UW2 (E2): [l][ct][ks(4)][lane][8]
    const int r = t - 40960;
    const int lane = r & 63, ks = (r >> 6) & 3, ct = (r >> 8) & 7, l = r >> 11;
    src = upd_w2 + l * EMB * EMB + ((ct << 4) + (lane & 15)) * EMB + ks * 32 + ((lane >> 4) << 3);
    dh = g_wE2_h + r * 8; dl = g_wE2_l + r * 8;
  } else return;
  unsigned short hh[8], ll[8];
  #pragma unroll
  for (int m = 0; m < 8; m++) {
    const float x = src[m] * TSCALE;             // fold tanh 2*log2e pre-scale into weights
    const unsigned short hb = f2bf(x);
    hh[m] = hb;
    ll[m] = f2bf(x - bf2f(hb));
  }
  *(short8*)dh = *(const short8*)hh;
  *(short8*)dl = *(const short8*)ll;
}

__global__ __launch_bounds__(1024)
__attribute__((amdgpu_waves_per_eu(4, 4)))     // 4 waves/EU: 128 total regs/wave (64 arch + 64 AGPR)
void fsd_fused(
    const float* __restrict__ pos, const float* __restrict__ enc,
    const float* __restrict__ pos_emb, const float* __restrict__ na_emb,
    const int* __restrict__ T,
    const float* __restrict__ fc1_w, const float* __restrict__ fc1_b,
    const float* __restrict__ fc2_w, const float* __restrict__ fc2_b,
    const float* __restrict__ lin_w, const float* __restrict__ lin_b,
    const float* __restrict__ msg_w1, const float* __restrict__ msg_b1,
    const float* __restrict__ msg_b2,
    const float* __restrict__ upd_b1, const float* __restrict__ upd_b2,
    float* __restrict__ out)
{
  __shared__ __align__(16) float h32[NN][UPAD];
  __shared__ __align__(16) float u_s[NN][UPAD];     // pos_emb staging; hid32 in E1
  __shared__ __align__(16) float v_s[NN][UPAD];
  __shared__ __align__(16) unsigned short hfH[8][64][8],  hfL[8][64][8];   // h A-frags
  __shared__ __align__(16) unsigned short agfH[8][64][8], agfL[8][64][8];  // aggr A-frags; hid frags in E2
  __shared__ __align__(16) unsigned short w2fH[4][8][64][8], w2fL[4][8][64][8]; // W2 B-frags 32x32 (64 KB)
  __shared__ float e_s[EMB];
  __shared__ float c5_s[EMB];
  __shared__ float b2m_s[EMB];
  __shared__ float clsU[2][EMB], clsV[2][EMB];
  __shared__ float enc_s[ENCD];
  __shared__ float hidA_s[64];
  __shared__ float posx_s[NN], posy_s[NN];
  __shared__ int   T_s[NN];

  const int b    = blockIdx.x;
  const int tid  = threadIdx.x;
  const int w    = tid >> 6, lane = tid & 63;   // 16 waves
  const int o    = tid & 127, g8 = tid >> 7;    // [0,8): node-group for VALU phases
  const int l15  = lane & 15, l4 = lane >> 4;

  // ---------------- Phase A: decoder_fc -> e_s ----------------
  if (tid < ENCD) enc_s[tid] = enc[b * ENCD + tid];
  if (tid < NN) {
    posx_s[tid] = pos[(b * NN + tid) * 2 + 0];
    posy_s[tid] = pos[(b * NN + tid) * 2 + 1];
    T_s[tid]    = T[b * NN + tid];
  }
  __syncthreads();
  if (tid < 64) {
    float a = fc1_b[tid];
    const float* wr = fc1_w + tid * ENCD;
    #pragma unroll 8
    for (int k = 0; k < ENCD; k++) a += enc_s[k] * wr[k];
    hidA_s[tid] = fast_tanh(a);
  }
  __syncthreads();
  if (tid < EMB) {
    float a = fc2_b[tid];
    const float* wr = fc2_w + tid * 64;
    #pragma unroll 8
    for (int k = 0; k < 64; k++) a += hidA_s[k] * wr[k];
    e_s[tid] = a;
  }
  float* pe_s = &u_s[0][0];
  for (int idx = tid; idx < NN * PEMB; idx += 1024)
    pe_s[idx] = pos_emb[b * NN * PEMB + idx];
  __syncthreads();

  // ---------------- Phase B: h0 = x @ lin_w^T + lin_b (unscaled, no tanh) ----------------
  {
    const float nav = na_emb[b];
    const float* wr = lin_w + o * IND;
    float ebias = lin_b[o] + nav * wr[PEMB];
    #pragma unroll 8
    for (int k = 0; k < EMB; k++) ebias += e_s[k] * wr[65 + k];
    float acc[4];
    #pragma unroll
    for (int n = 0; n < 4; n++) acc[n] = ebias;
    for (int kc = 0; kc < PEMB; kc += 16) {
      float wreg[16];
      #pragma unroll
      for (int q = 0; q < 16; q++) wreg[q] = wr[kc + q];
      #pragma unroll
      for (int n = 0; n < 4; n++)
        acc[n] += dot16_lds(&pe_s[(g8 + 8 * n) * PEMB + kc], wreg);
    }
    __syncthreads();   // pe reads done before u_s reuse
    #pragma unroll
    for (int n = 0; n < 4; n++) h32[g8 + 8 * n][o] = acc[n];
  }
  __syncthreads();
  if (w < 8) cvt_plane(h32, hfH, hfL, w, lane);
  __syncthreads();

  // ---------------- Layer loop ----------------
  for (int l = 0; l < NLAY; l++) {
    const float* b1  = msg_b1 + l * EMB;
    const float* b2  = msg_b2 + l * EMB;
    const float* ub1 = upd_b1 + l * EMB;
    const float* ub2 = upd_b2 + l * EMB;
    const float* w1  = msg_w1 + l * EMB * W1C;   // c5/cls columns only

    // ---- stage (all tanh-input tables PRE-SCALED by TSCALE) ----
    if (tid < EMB) { c5_s[tid] = w1[tid * W1C + 260] * TSCALE; b2m_s[tid] = b2[tid] * TSCALE; }
    {
      const int c = (tid >> 7) & 1, oo = tid & 127;
      if (tid < 256)      clsU[c][oo] = (b1[oo] + w1[oo * W1C + 258 + c]) * TSCALE;
      else if (tid < 512) clsV[c][oo] = w1[oo * W1C + 256 + c] * TSCALE;
    }
    {
      const unsigned short* sH = g_wD_h + l * 16384;
      const unsigned short* sL = g_wD_l + l * 16384;
      unsigned short* dH = &w2fH[0][0][0][0];
      unsigned short* dL = &w2fL[0][0][0][0];
      for (int idx = tid; idx < 2048; idx += 1024) {
        *(short8*)(dH + idx * 8) = *(const short8*)(sH + idx * 8);
        *(short8*)(dL + idx * 8) = *(const short8*)(sL + idx * 8);
      }
    }
    __syncthreads();   // (1) tables + w2f ready, h-frags ready

    // ---- Phase C: u,v = h @ W1parts^T via MFMA (outputs scaled); wave w owns col-tile w ----
    {
      const int part = w >> 3;                   // 0 -> u, 1 -> v
      const int col  = ((w & 7) << 4) + l15;
      floatx4 acc0 = {0.f,0.f,0.f,0.f}, acc1 = {0.f,0.f,0.f,0.f};
      #pragma unroll
      for (int ks = 0; ks < 4; ks++) {
        const int idx = (((l * 16 + w) * 4 + ks) * 64 + lane) * 8;
        const short8 bh = *(const short8*)(g_wC_h + idx);
        const short8 bl = *(const short8*)(g_wC_l + idx);
        const short8 ah0 = *(const short8*)&hfH[ks*2+0][lane][0];
        const short8 al0 = *(const short8*)&hfL[ks*2+0][lane][0];
        const short8 ah1 = *(const short8*)&hfH[ks*2+1][lane][0];
        const short8 al1 = *(const short8*)&hfL[ks*2+1][lane][0];
        acc0 = mfma3(ah0, al0, bh, bl, acc0);
        acc1 = mfma3(ah1, al1, bh, bl, acc1);
      }
      float (*dst)[UPAD] = part ? v_s : u_s;
      const float (*tab)[EMB] = part ? clsV : clsU;
      #pragma unroll
      for (int q = 0; q < 4; q++) {
        const int r0 = (l4 << 2) + q;
        const int r1 = r0 + 16;
        dst[r0][col] = acc0[q] + tab[T_s[r0]][col];
        dst[r1][col] = acc1[q] + tab[T_s[r1]][col];
      }
    }
    __syncthreads();   // (2) u,v ready

    // ---- Phase D (32x32x16): wave w owns dst nodes 2w, 2w+1 sequentially.
    //      M=32 spans ALL source nodes; acc = one f32x16 (16 AGPRs) per nt.
    //      Sched: (DS_READ 4, MFMA 4) groups -> 4 B-reads in flight (r13's 1:1
    //      pin exposed full ds_read latency; 16 B-regs live, fits 64-arch). ----
    {
      const int j32 = lane & 31;          // A row = source node
      const int khi = (lane >> 5) << 3;   // k-subrange within frag
      const float pjx = posx_s[j32], pjy = posy_s[j32];
      #pragma unroll 1
      for (int ii = 0; ii < 2; ii++) {
        const int i = (w << 1) + ii;
        const float dxx = pjx - posx_s[i], dyy = pjy - posy_s[i];
        const float d = sqrtf(dxx * dxx + dyy * dyy);
        const short8 aF0 = build_t32(&u_s[i][  0 + khi], &v_s[j32][  0 + khi], &c5_s[  0 + khi], d);
        const short8 aF1 = build_t32(&u_s[i][ 16 + khi], &v_s[j32][ 16 + khi], &c5_s[ 16 + khi], d);
        const short8 aF2 = build_t32(&u_s[i][ 32 + khi], &v_s[j32][ 32 + khi], &c5_s[ 32 + khi], d);
        const short8 aF3 = build_t32(&u_s[i][ 48 + khi], &v_s[j32][ 48 + khi], &c5_s[ 48 + khi], d);
        const short8 aF4 = build_t32(&u_s[i][ 64 + khi], &v_s[j32][ 64 + khi], &c5_s[ 64 + khi], d);
        const short8 aF5 = build_t32(&u_s[i][ 80 + khi], &v_s[j32][ 80 + khi], &c5_s[ 80 + khi], d);
        const short8 aF6 = build_t32(&u_s[i][ 96 + khi], &v_s[j32][ 96 + khi], &c5_s[ 96 + khi], d);
        const short8 aF7 = build_t32(&u_s[i][112 + khi], &v_s[j32][112 + khi], &c5_s[112 + khi], d);

        #pragma unroll 1
        for (int nt = 0; nt < 4; nt++) {
          floatx16 acc = {0.f,0.f,0.f,0.f,0.f,0.f,0.f,0.f,0.f,0.f,0.f,0.f,0.f,0.f,0.f,0.f};
          // kt-pairs: 4 b128 reads then 4 MFMAs (same per-acc MFMA order as r13)
          #define DPAIR(k0_, aFa, aFb) { \
            const short8 bl0 = *(const short8*)&w2fL[nt][k0_    ][lane][0]; \
            const short8 bh0 = *(const short8*)&w2fH[nt][k0_    ][lane][0]; \
            const short8 bl1 = *(const short8*)&w2fL[nt][k0_ + 1][lane][0]; \
            const short8 bh1 = *(const short8*)&w2fH[nt][k0_ + 1][lane][0]; \
            acc = __builtin_amdgcn_mfma_f32_32x32x16_bf16(aFa, bl0, acc, 0, 0, 0); \
            acc = __builtin_amdgcn_mfma_f32_32x32x16_bf16(aFa, bh0, acc, 0, 0, 0); \
            acc = __builtin_amdgcn_mfma_f32_32x32x16_bf16(aFb, bl1, acc, 0, 0, 0); \
            acc = __builtin_amdgcn_mfma_f32_32x32x16_bf16(aFb, bh1, acc, 0, 0, 0); }
          DPAIR(0, aF0, aF1) DPAIR(2, aF2, aF3) DPAIR(4, aF4, aF5) DPAIR(6, aF6, aF7)
          #undef DPAIR
          // pin: 4 DS_READ then 4 MFMA, x4 -> 4 B-reads in flight, <=16 B-regs live
          #pragma unroll
          for (int g = 0; g < 4; g++) {
            __builtin_amdgcn_sched_group_barrier(0x100, 4, 0);  // DS_READ x4
            __builtin_amdgcn_sched_group_barrier(0x008, 4, 0);  // MFMA   x4
          }
          __builtin_amdgcn_sched_barrier(0);
          // epilogue: C/D col=lane&31; rows split across reg & lane>>5 -> 16 tanh + xor32
          const int c = (nt << 5) + j32;
          const float b2c = b2m_s[c];
          float p0 = 0.f, p1 = 0.f;
          #pragma unroll
          for (int rr = 0; rr < 16; rr += 2) {
            p0 += tanh2(acc[rr]     + b2c);
            p1 += tanh2(acc[rr + 1] + b2c);
          }
          float p = p0 + p1;
          p += __shfl_xor(p, 32);
          if (lane < 32) {
            const int plane = (nt << 1) + (i >> 4);
            const int slot  = (i & 15) + (((c >> 3) & 3) << 4);
            const int elem  = c & 7;
            const unsigned short hb = f2bf(p);
            agfH[plane][slot][elem] = hb;
            agfL[plane][slot][elem] = f2bf(p - bf2f(hb));
          }
        }
      }
    }
    __syncthreads();   // (3) agf complete; u_s free

    // ---- Phase E1: hid = tanh2([h|aggr] @ uw1s^T + ub1*S) -> u_s.
    //      wave w: col-tile ct = w&7, row-half jt = w>>3 ----
    {
      const int ct = w & 7, jt = w >> 3;
      const int col = (ct << 4) + l15;
      const float bo = ub1[col] * TSCALE;
      floatx4 acc = {0.f,0.f,0.f,0.f};
      #pragma unroll
      for (int ks = 0; ks < 8; ks++) {
        const int idx = (((l * 8 + ct) * 8 + ks) * 64 + lane) * 8;
        const short8 bh = *(const short8*)(g_wE1_h + idx);
        const short8 bl = *(const short8*)(g_wE1_l + idx);
        short8 ah, al;
        if (ks < 4) {
          ah = *(const short8*)&hfH[ks*2+jt][lane][0];
          al = *(const short8*)&hfL[ks*2+jt][lane][0];
        } else {
          ah = *(const short8*)&agfH[(ks-4)*2+jt][lane][0];
          al = *(const short8*)&agfL[(ks-4)*2+jt][lane][0];
        }
        acc = mfma3(ah, al, bh, bl, acc);
      }
      #pragma unroll
      for (int q = 0; q < 4; q++) {
        const int r = (jt << 4) + (l4 << 2) + q;
        u_s[r][col] = tanh2(acc[q] + bo);        // u_s reused as hid32 (unscaled output)
      }
    }
    __syncthreads();   // (4) hid32 ready AND all agf/hf reads done

    if (w < 8) cvt_plane(u_s, agfH, agfL, w, lane);   // hid frags into agf
    __syncthreads();   // (5)

    // ---- Phase E2: h += tanh2(hid @ uw2s^T + ub2*S); same (ct, jt) split ----
    {
      const int ct = w & 7, jt = w >> 3;
      const int col = (ct << 4) + l15;
      const float bo = ub2[col] * TSCALE;
      floatx4 acc = {0.f,0.f,0.f,0.f};
      #pragma unroll
      for (int ks = 0; ks < 4; ks++) {
        const int idx = (((l * 8 + ct) * 4 + ks) * 64 + lane) * 8;
        const short8 bh = *(const short8*)(g_wE2_h + idx);
        const short8 bl = *(const short8*)(g_wE2_l + idx);
        const short8 ah = *(const short8*)&agfH[ks*2+jt][lane][0];
        const short8 al = *(const short8*)&agfL[ks*2+jt][lane][0];
        acc = mfma3(ah, al, bh, bl, acc);
      }
      #pragma unroll
      for (int q = 0; q < 4; q++) {
        const int r = (jt << 4) + (l4 << 2) + q;
        h32[r][col] += tanh2(acc[q] + bo);
      }
    }
    __syncthreads();   // (6) h updated

    if (l + 1 < NLAY) {
      if (w < 8) cvt_plane(h32, hfH, hfL, w, lane);
      __syncthreads();
    }
  }

  // ---------------- write out ----------------
  for (int idx = tid; idx < NN * EMB; idx += 1024)
    out[b * NN * EMB + idx] = h32[idx >> 7][idx & 127];
}

extern "C" void kernel_launch(void* const* d_in, const int* in_sizes, int n_in,
                              void* d_out, int out_size, void* d_ws, size_t ws_size,
                              hipStream_t stream) {
  const float* pos     = (const float*)d_in[0];
  const float* enc     = (const float*)d_in[1];
  const float* pos_emb = (const float*)d_in[2];
  const float* na_emb  = (const float*)d_in[3];
  const int*   T       = (const int*)d_in[4];
  // d_in[5] = num_agents (compile-time 32)
  const float* fc1_w = (const float*)d_in[6];
  const float* fc1_b = (const float*)d_in[7];
  const float* fc2_w = (const float*)d_in[8];
  const float* fc2_b = (const float*)d_in[9];
  const float* lin_w = (const float*)d_in[10];
  const float* lin_b = (const float*)d_in[11];
  const float* msg_w1 = (const float*)d_in[12];
  const float* msg_b1 = (const float*)d_in[13];
  const float* msg_w2 = (const float*)d_in[14];
  const float* msg_b2 = (const float*)d_in[15];
  const float* upd_w1 = (const float*)d_in[16];
  const float* upd_b1 = (const float*)d_in[17];
  const float* upd_w2 = (const float*)d_in[18];
  const float* upd_b2 = (const float*)d_in[19];

  wconv<<<192, 256, 0, stream>>>(msg_w1, msg_w2, upd_w1, upd_w2);
  fsd_fused<<<256, 1024, 0, stream>>>(pos, enc, pos_emb, na_emb, T,
      fc1_w, fc1_b, fc2_w, fc2_b, lin_w, lin_b,
      msg_w1, msg_b1, msg_b2, upd_b1, upd_b2,
      (float*)d_out);
}